// Round 6
// baseline (325.423 us; speedup 1.0000x reference)
//
#include <hip/hip_runtime.h>
#include <hip/hip_bf16.h>

#define T_TOK 2048
#define HDIM  2048
#define IDIM  1024
#define NE    16
#define NEX   17
#define NASSIGN (T_TOK*3)
#define TM    64

#define G1_NCT 16                   // IDIM/64
#define G2_NCT 32                   // HDIM/64
#define G1_NWG (TM*G1_NCT)          // 1024
#define G2_NWG (TM*G2_NCT)          // 2048

typedef __attribute__((ext_vector_type(8))) short bf16x8;
typedef __attribute__((ext_vector_type(4))) float f32x4;

#define WAITVM(N) asm volatile("s_waitcnt vmcnt(" #N ")" ::: "memory")
#define WAITLGKM  asm volatile("s_waitcnt lgkmcnt(0)" ::: "memory")
#define SCHEDB    __builtin_amdgcn_sched_barrier(0)
#define BARRIER   __builtin_amdgcn_s_barrier()

__device__ __forceinline__ unsigned short f2bf(float f) {
    union { float f; unsigned u; } v; v.f = f;
    unsigned r = v.u + 0x7fffu + ((v.u >> 16) & 1u);
    return (unsigned short)(r >> 16);
}
__device__ __forceinline__ unsigned pack2f(float a, float b) {
    __hip_bfloat162 h = __float22bfloat162_rn(float2{a, b});
    unsigned r;
    __builtin_memcpy(&r, &h, 4);
    return r;
}
__device__ __forceinline__ float fidx(const float4& v, int j) {
    return ((const float*)&v)[j];
}
// chunk swizzle within 128B LDS rows (rows of 64 bf16)
__device__ __forceinline__ int SW(int r) { return (r ^ (r >> 2)) & 7; }
__device__ __forceinline__ int lds_off(int row, int kelem) {
    return (row << 7) + ((((kelem >> 3) ^ SW(row))) << 4) + ((kelem & 7) << 1);
}
__device__ __forceinline__ f32x4 mfma16(bf16x8 a, bf16x8 b, f32x4 c) {
    return __builtin_amdgcn_mfma_f32_16x16x32_bf16(a, b, c, 0, 0, 0);
}
__device__ __forceinline__ void gload_lds16(const void* g, void* lds) {
    __builtin_amdgcn_global_load_lds(
        (const __attribute__((address_space(1))) unsigned*)g,
        (__attribute__((address_space(3))) unsigned*)lds, 16, 0, 0);
}

// ---------------- x fp32 -> bf16 ----------------
__global__ __launch_bounds__(256) void k_cvt(const float* __restrict__ x,
                                             unsigned short* __restrict__ xbf) {
    int i = blockIdx.x * 256 + threadIdx.x;
    float4 v = ((const float4*)x)[i];
    uint2 p{pack2f(v.x, v.y), pack2f(v.z, v.w)};
    ((uint2*)xbf)[i] = p;
}

// ---------------- Router ----------------
__global__ void k_router(const float* __restrict__ x, const float* __restrict__ Wr,
                         const float* __restrict__ bias, float* __restrict__ wtok,
                         int* __restrict__ idxtok, int* __restrict__ counts) {
    int t = blockIdx.x;
    int lane = threadIdx.x & 63;
    int wave = threadIdx.x >> 6;
    __shared__ float lg[NE];
    const float4* xr = (const float4*)(x + (size_t)t * HDIM);
    for (int e = wave; e < NE; e += 4) {
        const float4* wr = (const float4*)(Wr + (size_t)e * HDIM);
        float s = 0.f;
        for (int j = lane; j < HDIM / 4; j += 64) {
            float4 a = xr[j], b = wr[j];
            s += a.x*b.x + a.y*b.y + a.z*b.z + a.w*b.w;
        }
        #pragma unroll
        for (int d = 32; d; d >>= 1) s += __shfl_xor(s, d);
        if (lane == 0) lg[e] = s + bias[e];
    }
    __syncthreads();
    if (threadIdx.x == 0) {
        float m = lg[0];
        #pragma unroll
        for (int e = 1; e < NE; e++) m = fmaxf(m, lg[e]);
        float p[NE]; float S = 0.f;
        #pragma unroll
        for (int e = 0; e < NE; e++) { p[e] = expf(lg[e] - m); S += p[e]; }
        int i0 = 0;
        #pragma unroll
        for (int e = 1; e < NE; e++) if (p[e] > p[i0]) i0 = e;
        int i1 = (i0 == 0) ? 1 : 0;
        for (int e = 0; e < NE; e++) if (e != i0 && p[e] > p[i1]) i1 = e;
        float v0 = p[i0] / S, v1 = p[i1] / S;
        float wsum = v0 + v1 + 1e-9f;
        wtok[t*2+0] = v0 / wsum;
        wtok[t*2+1] = v1 / wsum;
        idxtok[t*2+0] = i0;
        idxtok[t*2+1] = i1;
        atomicAdd(&counts[i0], 1);
        atomicAdd(&counts[i1], 1);
    }
}

// ---------------- scan + tile work-list ----------------
__global__ void k_scan(const int* __restrict__ counts, int* __restrict__ offs,
                       int* __restrict__ cursor, int4* __restrict__ tiles) {
    if (threadIdx.x == 0) {
        int acc = 0;
        for (int e = 0; e < NEX; e++) {
            offs[e] = acc; cursor[e] = acc;
            acc += (e < NE) ? counts[e] : T_TOK;
        }
        offs[NEX] = acc;
        int nt = 0;
        for (int e = 0; e < NEX; e++) {
            for (int r = offs[e]; r < offs[e+1]; r += 128) {
                tiles[nt] = int4{r, min(128, offs[e+1] - r), e, 0};
                nt++;
            }
        }
        for (; nt < TM; nt++) tiles[nt] = int4{0, 0, 0, 0};
    }
}

__global__ void k_scatter(const int* __restrict__ idxtok, const float* __restrict__ wtok,
                          int* __restrict__ cursor, const int* __restrict__ offs,
                          int* __restrict__ rows, float* __restrict__ wrow) {
    int t = blockIdx.x * blockDim.x + threadIdx.x;
    if (t >= T_TOK) return;
    #pragma unroll
    for (int k = 0; k < 2; k++) {
        int e = idxtok[t*2+k];
        int pos = atomicAdd(&cursor[e], 1);
        rows[pos] = t;
        wrow[pos] = wtok[t*2+k];
    }
    int p16 = offs[NE] + t;
    rows[p16] = t;
    wrow[p16] = 1.0f;
}

// ---------------- GEMM1: act = w * silu(X@Wg) * (X@Wu) -> bf16 ----------------
// tile 128x64, BK=64, 512 thr (8 waves 2x4). Counted-vmcnt pipeline (T4):
// A via global_load_lds (pre-swizzled src), weights reg-staged 1 step ahead,
// raw s_barrier so loads stay in flight across barriers.
__global__ __launch_bounds__(512) void k_gemm1(
        const unsigned short* __restrict__ xbf,
        const float* __restrict__ Wg, const float* __restrict__ Wu,
        const float* __restrict__ sWg, const float* __restrict__ sWu,
        const int4* __restrict__ tiles, const int* __restrict__ rows,
        const float* __restrict__ wrow, unsigned short* __restrict__ act) {
    int bid = blockIdx.x;
    int wg = (bid & 7) * (G1_NWG >> 3) + (bid >> 3);   // XCD-chunked
    int ti = wg & (TM - 1);
    int ct = wg >> 6;

    int4 tl = tiles[ti];
    int nrows = tl.y;
    if (nrows == 0) return;
    int rs = tl.x, e = tl.z;
    const float* wgp = (e < NE) ? Wg + (size_t)e * HDIM * IDIM : sWg;
    const float* wup = (e < NE) ? Wu + (size_t)e * HDIM * IDIM : sWu;
    int n0 = ct * 64;

    __shared__ unsigned short As[2][128 * 64];
    __shared__ unsigned short Bs[2][64 * 64];
    __shared__ unsigned short Us[2][64 * 64];
    __shared__ int rloc[128];

    int tid = threadIdx.x;
    if (tid < 128) rloc[tid] = rows[rs + min(tid, nrows - 1)];
    __syncthreads();

    int l = tid & 63, w = tid >> 6;
    // A: pre-swizzled per-lane global source, linear LDS dest (wave-chunked)
    int ar0 = w * 8 + (l >> 3);
    int ar1 = 64 + ar0;
    const unsigned short* asrc0 = xbf + (size_t)rloc[ar0] * HDIM + (((l & 7) ^ SW(ar0)) << 3);
    const unsigned short* asrc1 = xbf + (size_t)rloc[ar1] * HDIM + (((l & 7) ^ SW(ar1)) << 3);

    // weights: 4 consecutive n at rows kb, kb+1 per matrix
    int n4 = (tid & 15) << 2;
    int kb = (tid >> 4) << 1;
    const float* gsrc = wgp + (size_t)kb * IDIM + n0 + n4;
    const float* usrc = wup + (size_t)kb * IDIM + n0 + n4;

    int wr = (w >> 2) << 6;
    int wc = (w & 3) << 4;
    int fr = l & 15;
    int fk = (l >> 4) << 3;

    float4 gR0, gR1, uR0, uR1;

    #define G1_LOADW(K0) do { \
        gR0 = *(const float4*)(gsrc + (size_t)(K0) * IDIM); \
        gR1 = *(const float4*)(gsrc + (size_t)(K0) * IDIM + IDIM); \
        uR0 = *(const float4*)(usrc + (size_t)(K0) * IDIM); \
        uR1 = *(const float4*)(usrc + (size_t)(K0) * IDIM + IDIM); \
    } while (0)

    #define G1_GLOADA(K0, B) do { \
        gload_lds16(asrc0 + (K0), (char*)As[B] + w * 1024); \
        gload_lds16(asrc1 + (K0), (char*)As[B] + 8192 + w * 1024); \
    } while (0)

    #define G1_WRITEW(B) do { \
        _Pragma("unroll") \
        for (int i = 0; i < 4; ++i) { \
            int n = n4 + i; \
            *(unsigned*)((char*)Bs[B] + lds_off(n, kb)) = pack2f(fidx(gR0,i), fidx(gR1,i)); \
            *(unsigned*)((char*)Us[B] + lds_off(n, kb)) = pack2f(fidx(uR0,i), fidx(uR1,i)); \
        } \
    } while (0)

    f32x4 accg[4] = {}, accu[4] = {};
    const int NK = HDIM / 64;
    const int KLAST = (NK - 1) * 64;

    // prologue: outstanding after = loadW(1) only
    G1_LOADW(0);            // 4 ops
    G1_GLOADA(0, 0);        // 2 ops
    SCHEDB;
    WAITVM(2);              // retire loadW(0), keep A(0) flying
    G1_WRITEW(0);
    G1_LOADW(64);           // 4 ops
    SCHEDB;
    WAITVM(4);              // retire A(0), keep loadW(1) flying
    WAITLGKM;
    BARRIER;

    for (int k = 0; k < NK; ++k) {
        int buf = k & 1;
        int kA = min((k + 1) * 64, KLAST);
        int kW = min((k + 2) * 64, KLAST);
        G1_GLOADA(kA, buf ^ 1);          // 2 ops
        SCHEDB;
        WAITVM(2);                       // retire loadW(k+1), keep A(k+1)
        G1_WRITEW(buf ^ 1);
        G1_LOADW(kW);                    // 4 ops
        SCHEDB;
        #pragma unroll
        for (int kh = 0; kh < 2; ++kh) {
            int kk = (kh << 5) + fk;
            bf16x8 a[4], bg, bu;
            #pragma unroll
            for (int m = 0; m < 4; ++m)
                a[m] = *(const bf16x8*)((const char*)As[buf] + lds_off(wr + m * 16 + fr, kk));
            bg = *(const bf16x8*)((const char*)Bs[buf] + lds_off(wc + fr, kk));
            bu = *(const bf16x8*)((const char*)Us[buf] + lds_off(wc + fr, kk));
            #pragma unroll
            for (int m = 0; m < 4; ++m) {
                accg[m] = mfma16(a[m], bg, accg[m]);
                accu[m] = mfma16(a[m], bu, accu[m]);
            }
        }
        WAITVM(4);                       // retire A(k+1), keep loadW(k+2)
        WAITLGKM;
        BARRIER;
    }
    WAITVM(0);

    int crow = (l >> 4) << 2;
    int ccol = l & 15;
    #pragma unroll
    for (int m = 0; m < 4; ++m) {
        #pragma unroll
        for (int reg = 0; reg < 4; ++reg) {
            int r = wr + m * 16 + crow + reg;
            if (r < nrows) {
                float wv = wrow[rs + r];
                float g = accg[m][reg], u = accu[m][reg];
                act[(size_t)(rs + r) * IDIM + n0 + wc + ccol] =
                    f2bf(g / (1.f + __expf(-g)) * u * wv);
            }
        }
    }
    #undef G1_LOADW
    #undef G1_GLOADA
    #undef G1_WRITEW
}

// ---------------- GEMM2: out[tok] += act @ Wd ----------------
__global__ __launch_bounds__(512) void k_gemm2(
        const unsigned short* __restrict__ act,
        const float* __restrict__ Wd, const float* __restrict__ sWd,
        const int4* __restrict__ tiles, const int* __restrict__ rows,
        float* __restrict__ out) {
    int bid = blockIdx.x;
    int wg = (bid & 7) * (G2_NWG >> 3) + (bid >> 3);
    int ti = wg & (TM - 1);
    int ct = wg >> 6;

    int4 tl = tiles[ti];
    int nrows = tl.y;
    if (nrows == 0) return;
    int rs = tl.x, e = tl.z;
    const float* wdp = (e < NE) ? Wd + (size_t)e * IDIM * HDIM : sWd;
    int n0 = ct * 64;

    __shared__ unsigned short As[2][128 * 64];
    __shared__ unsigned short Bs[2][64 * 64];
    __shared__ int rloc[128];

    int tid = threadIdx.x;
    if (tid < 128) rloc[tid] = rows[rs + min(tid, nrows - 1)];
    __syncthreads();

    int l = tid & 63, w = tid >> 6;
    int ar0 = w * 8 + (l >> 3);
    int ar1 = 64 + ar0;
    const unsigned short* asrc0 = act + (size_t)(rs + ar0) * IDIM + (((l & 7) ^ SW(ar0)) << 3);
    const unsigned short* asrc1 = act + (size_t)(rs + ar1) * IDIM + (((l & 7) ^ SW(ar1)) << 3);

    int n4 = (tid & 15) << 2;
    int kb = (tid >> 4) << 1;
    const float* dsrc = wdp + (size_t)kb * HDIM + n0 + n4;

    int wr = (w >> 2) << 6;
    int wc = (w & 3) << 4;
    int fr = l & 15;
    int fk = (l >> 4) << 3;

    float4 dR0, dR1;

    #define G2_LOADW(K0) do { \
        dR0 = *(const float4*)(dsrc + (size_t)(K0) * HDIM); \
        dR1 = *(const float4*)(dsrc + (size_t)(K0) * HDIM + HDIM); \
    } while (0)

    #define G2_GLOADA(K0, B) do { \
        gload_lds16(asrc0 + (K0), (char*)As[B] + w * 1024); \
        gload_lds16(asrc1 + (K0), (char*)As[B] + 8192 + w * 1024); \
    } while (0)

    #define G2_WRITEW(B) do { \
        _Pragma("unroll") \
        for (int i = 0; i < 4; ++i) { \
            int n = n4 + i; \
            *(unsigned*)((char*)Bs[B] + lds_off(n, kb)) = pack2f(fidx(dR0,i), fidx(dR1,i)); \
        } \
    } while (0)

    f32x4 acc[4] = {};
    const int NK = IDIM / 64;
    const int KLAST = (NK - 1) * 64;

    G2_LOADW(0);            // 2 ops
    G2_GLOADA(0, 0);        // 2 ops
    SCHEDB;
    WAITVM(2);              // retire loadW(0)
    G2_WRITEW(0);
    G2_LOADW(64);           // 2 ops
    SCHEDB;
    WAITVM(2);              // retire A(0), keep loadW(1)
    WAITLGKM;
    BARRIER;

    for (int k = 0; k < NK; ++k) {
        int buf = k & 1;
        int kA = min((k + 1) * 64, KLAST);
        int kW = min((k + 2) * 64, KLAST);
        G2_GLOADA(kA, buf ^ 1);          // 2 ops
        SCHEDB;
        WAITVM(2);                       // retire loadW(k+1), keep A(k+1)
        G2_WRITEW(buf ^ 1);
        G2_LOADW(kW);                    // 2 ops
        SCHEDB;
        #pragma unroll
        for (int kh = 0; kh < 2; ++kh) {
            int kk = (kh << 5) + fk;
            bf16x8 a[4], b;
            #pragma unroll
            for (int m = 0; m < 4; ++m)
                a[m] = *(const bf16x8*)((const char*)As[buf] + lds_off(wr + m * 16 + fr, kk));
            b = *(const bf16x8*)((const char*)Bs[buf] + lds_off(wc + fr, kk));
            #pragma unroll
            for (int m = 0; m < 4; ++m)
                acc[m] = mfma16(a[m], b, acc[m]);
        }
        WAITVM(2);                       // retire A(k+1), keep loadW(k+2)
        WAITLGKM;
        BARRIER;
    }
    WAITVM(0);

    int crow = (l >> 4) << 2;
    int ccol = l & 15;
    #pragma unroll
    for (int m = 0; m < 4; ++m) {
        #pragma unroll
        for (int reg = 0; reg < 4; ++reg) {
            int r = wr + m * 16 + crow + reg;
            if (r < nrows) {
                atomicAdd(&out[(size_t)rloc[r] * HDIM + n0 + wc + ccol], acc[m][reg]);
            }
        }
    }
    #undef G2_LOADW
    #undef G2_GLOADA
    #undef G2_WRITEW
}

extern "C" void kernel_launch(void* const* d_in, const int* in_sizes, int n_in,
                              void* d_out, int out_size, void* d_ws, size_t ws_size,
                              hipStream_t stream) {
    const float* x    = (const float*)d_in[0];
    const float* Wr   = (const float*)d_in[1];
    const float* bias = (const float*)d_in[2];
    const float* Wg   = (const float*)d_in[3];
    const float* Wu   = (const float*)d_in[4];
    const float* Wd   = (const float*)d_in[5];
    const float* sWg  = (const float*)d_in[6];
    const float* sWu  = (const float*)d_in[7];
    const float* sWd  = (const float*)d_in[8];
    float* out = (float*)d_out;

    char* p = (char*)d_ws;
    int*   counts = (int*)p;                 p += 256;
    int*   offs   = (int*)p;                 p += 256;
    int*   cursor = (int*)p;                 p += 256;
    int4*  tiles  = (int4*)p;                p += TM * sizeof(int4);
    int*   idxtok = (int*)p;                 p += (size_t)T_TOK * 2 * sizeof(int);
    float* wtok   = (float*)p;               p += (size_t)T_TOK * 2 * sizeof(float);
    int*   rows   = (int*)p;                 p += (size_t)NASSIGN * sizeof(int);
    float* wrow   = (float*)p;               p += (size_t)NASSIGN * sizeof(float);
    unsigned short* act = (unsigned short*)p; p += (size_t)NASSIGN * IDIM * sizeof(unsigned short);
    unsigned short* xbf = (unsigned short*)p; // 8.4MB

    hipMemsetAsync(counts, 0, 256, stream);
    hipMemsetAsync(d_out, 0, (size_t)out_size * sizeof(float), stream);

    k_cvt<<<dim3(T_TOK * HDIM / 1024), dim3(256), 0, stream>>>(x, xbf);
    k_router<<<dim3(T_TOK), dim3(256), 0, stream>>>(x, Wr, bias, wtok, idxtok, counts);
    k_scan<<<dim3(1), dim3(64), 0, stream>>>(counts, offs, cursor, tiles);
    k_scatter<<<dim3((T_TOK + 255) / 256), dim3(256), 0, stream>>>(idxtok, wtok, cursor, offs, rows, wrow);
    k_gemm1<<<dim3(G1_NWG), dim3(512), 0, stream>>>(xbf, Wg, Wu, sWg, sWu, tiles, rows, wrow, act);
    k_gemm2<<<dim3(G2_NWG), dim3(512), 0, stream>>>(act, Wd, sWd, tiles, rows, out);
}